// Round 9
// baseline (37.185 us; speedup 1.0000x reference)
//
#include <hip/hip_runtime.h>

#define BB 2
#define SDIM 1024
#define DDIM 128
#define K1_ROWS 2
#define II 8

#define F4GET(v,k) ((k)==0?(v).x:((k)==1?(v).y:((k)==2?(v).z:(v).w)))

typedef _Float16 h2v __attribute__((ext_vector_type(2)));
typedef _Float16 h8v __attribute__((ext_vector_type(8)));

__device__ __forceinline__ h2v habs2(h2v t) {
    unsigned u = __builtin_bit_cast(unsigned, t) & 0x7FFF7FFFu;
    return __builtin_bit_cast(h2v, u);
}

__device__ __forceinline__ float hdot2(h2v a, h2v b, float acc) {
#if __has_builtin(__builtin_amdgcn_fdot2)
    return __builtin_amdgcn_fdot2(a, b, acc, false);
#else
    acc = fmaf((float)a.x, (float)b.x, acc);
    return fmaf((float)a.y, (float)b.y, acc);
#endif
}

// ---------------- Kernel 1: projections + row dot products ----------------
// 1024 blocks x 256 thr. 2 rows/block; tid>>7 picks W1 half.
// Also emits w2h16[d] = f16(0.5*w2[d]) (block 0 only, idempotent).
__global__ __launch_bounds__(256) void proj_kernel(
    const float* __restrict__ x, const float* __restrict__ W1,
    const float* __restrict__ b1, const float* __restrict__ W2,
    const float* __restrict__ b2,
    ushort* __restrict__ hi16, ushort* __restrict__ hjb16,
    float* __restrict__ si2, float* __restrict__ sj2,
    ushort* __restrict__ w2h16)
{
    __shared__ float sX[K1_ROWS][DDIM];
    __shared__ float sRed[4][K1_ROWS];
    const int tid  = threadIdx.x;
    const int d    = tid & 127;
    const int half = tid >> 7;
    const int r0   = blockIdx.x * K1_ROWS;

    if (tid < K1_ROWS * DDIM / 4) {
        reinterpret_cast<float4*>(&sX[0][0])[tid] =
            reinterpret_cast<const float4*>(x + (size_t)r0 * DDIM)[tid];
    }
    __syncthreads();

    const float* Wh = W1 + (size_t)half * DDIM * DDIM;

    float acc[K1_ROWS];
    #pragma unroll
    for (int r = 0; r < K1_ROWS; ++r) acc[r] = 0.f;

    #pragma unroll 4
    for (int k = 0; k < DDIM; k += 4) {
        float4 xv[K1_ROWS];
        #pragma unroll
        for (int r = 0; r < K1_ROWS; ++r)
            xv[r] = *reinterpret_cast<const float4*>(&sX[r][k]);
        #pragma unroll
        for (int kk = 0; kk < 4; ++kk) {
            float w = Wh[(size_t)(k + kk) * DDIM + d];
            #pragma unroll
            for (int r = 0; r < K1_ROWS; ++r)
                acc[r] = fmaf(F4GET(xv[r], kk), w, acc[r]);
        }
    }

    if (half) {
        const float bv = b1[d];
        #pragma unroll
        for (int r = 0; r < K1_ROWS; ++r) acc[r] += bv;
    }

    ushort* hout = half ? hjb16 : hi16;
    #pragma unroll
    for (int r = 0; r < K1_ROWS; ++r) {
        _Float16 hv = (_Float16)acc[r];
        hout[(size_t)(r0 + r) * DDIM + d] = __builtin_bit_cast(ushort, hv);
    }

    const float wv = W2[d];
    if (!half && blockIdx.x == 0) {
        _Float16 wh = (_Float16)(0.5f * wv);
        w2h16[d] = __builtin_bit_cast(ushort, wh);
    }
    const int lane = tid & 63;
    const int wave = tid >> 6;
    #pragma unroll
    for (int r = 0; r < K1_ROWS; ++r) {
        float v = acc[r] * wv;
        #pragma unroll
        for (int off = 32; off >= 1; off >>= 1)
            v += __shfl_xor(v, off, 64);
        if (lane == 0) sRed[wave][r] = v;
    }
    __syncthreads();
    if (tid < K1_ROWS) {
        si2[r0 + tid] = 0.5f * (sRed[0][tid] + sRed[1][tid]);
    } else if (tid < 2 * K1_ROWS) {
        int r = tid - K1_ROWS;
        sj2[r0 + r] = 0.5f * (sRed[2][r] + sRed[3][r]) + b2[0];
    }
}

// ---------------- Kernel 2: pairwise edge logits (LDS-free) ----------------
// out[b,i,j] = si2[b,i] + sj2[b,j] + sum_d |hi[b,i,d]+hjb[b,j,d]| * 0.5*w2[d]
// lane -> j-column: hjb16 row j resident in 32 VGPRs (f16), loaded once.
// Wave iterates II=8 i-rows; hi16 row + W are wave-uniform loads (broadcast).
// No LDS, no barriers. Stores: 64 lanes x 4B contiguous (coalesced).
__global__ __launch_bounds__(256) void edge_kernel(
    const ushort* __restrict__ hi16, const ushort* __restrict__ hjb16,
    const float* __restrict__ si2, const float* __restrict__ sj2,
    const ushort* __restrict__ w2h16, float* __restrict__ out)
{
    const int tid  = threadIdx.x;
    const int lane = tid & 63;
    const int wid  = blockIdx.x * 4 + (tid >> 6);   // 0..4095
    const int jg   = wid & 15;                      // j group (64 cols)
    const int ig   = (wid >> 4) & 127;              // i group (8 rows)
    const int b    = wid >> 11;
    const int j    = (jg << 6) + lane;
    const int i0   = ig * II;
    const int rowb = b << 10;                       // b*SDIM

    // Per-lane B row (32 VGPR, static indexing only).
    h8v Bv[16];
    {
        const h8v* bp = reinterpret_cast<const h8v*>(hjb16 + (size_t)(rowb + j) * DDIM);
        #pragma unroll
        for (int ch = 0; ch < 16; ++ch) Bv[ch] = bp[ch];
    }
    // Wave-uniform W (0.5*w2 as f16; 32 VGPR after broadcast).
    h8v Wv[16];
    {
        const h8v* wp = reinterpret_cast<const h8v*>(w2h16);
        #pragma unroll
        for (int ch = 0; ch < 16; ++ch) Wv[ch] = wp[ch];
    }
    const float sjv = sj2[rowb + j];

    #pragma unroll 1
    for (int ii = 0; ii < II; ++ii) {
        const int i = i0 + ii;
        // Wave-uniform A row (broadcast load, VMEM/SMEM pipe).
        const h8v* hp = reinterpret_cast<const h8v*>(hi16 + (size_t)(rowb + i) * DDIM);
        h8v H[16];
        #pragma unroll
        for (int ch = 0; ch < 16; ++ch) H[ch] = hp[ch];

        float a0 = 0.f, a1 = 0.f, a2 = 0.f, a3 = 0.f;
        #pragma unroll
        for (int ch = 0; ch < 16; ++ch) {
            const h2v* bp2 = reinterpret_cast<const h2v*>(&Bv[ch]);
            const h2v* hp2 = reinterpret_cast<const h2v*>(&H[ch]);
            const h2v* wp2 = reinterpret_cast<const h2v*>(&Wv[ch]);
            h2v t0 = bp2[0] + hp2[0];   // v_pk_add_f16
            h2v t1 = bp2[1] + hp2[1];
            h2v t2 = bp2[2] + hp2[2];
            h2v t3 = bp2[3] + hp2[3];
            a0 = hdot2(habs2(t0), wp2[0], a0);   // v_and + v_dot2_f32_f16
            a1 = hdot2(habs2(t1), wp2[1], a1);
            a2 = hdot2(habs2(t2), wp2[2], a2);
            a3 = hdot2(habs2(t3), wp2[3], a3);
        }
        const float res = ((a0 + a1) + (a2 + a3)) + si2[rowb + i] + sjv;
        out[((size_t)(rowb + i) << 10) + j] = res;   // coalesced 256B/wave
    }
}

extern "C" void kernel_launch(void* const* d_in, const int* in_sizes, int n_in,
                              void* d_out, int out_size, void* d_ws, size_t ws_size,
                              hipStream_t stream) {
    const float* x  = (const float*)d_in[0];
    const float* W1 = (const float*)d_in[1];
    const float* b1 = (const float*)d_in[2];
    const float* W2 = (const float*)d_in[3];
    const float* b2 = (const float*)d_in[4];
    float* out = (float*)d_out;

    char* ws = (char*)d_ws;
    ushort* hi16   = (ushort*)ws;                                  // B*S*D f16
    ushort* hjb16  = hi16 + (size_t)BB * SDIM * DDIM;              // B*S*D f16
    float*  si2    = (float*)(hjb16 + (size_t)BB * SDIM * DDIM);   // B*S f32
    float*  sj2    = si2 + (size_t)BB * SDIM;                      // B*S f32
    ushort* w2h16  = (ushort*)(sj2 + (size_t)BB * SDIM);           // D f16

    proj_kernel<<<BB * SDIM / K1_ROWS, 256, 0, stream>>>(x, W1, b1, W2, b2,
                                                         hi16, hjb16, si2, sj2, w2h16);
    edge_kernel<<<SDIM / 64 * (SDIM / II) * BB / 4, 256, 0, stream>>>(hi16, hjb16, si2, sj2, w2h16, out);
}